// Round 9
// baseline (146.175 us; speedup 1.0000x reference)
//
#include <hip/hip_runtime.h>
#include <math.h>

#define BB 2
#define KK 8
#define NB 256            // histogram bins over error in [0,2]
#define HALF_NB_F 128.0f
#define FAR_CUT 5.545177444479562f  // ln(256): ssq above this && !lab => bin 0

#define PXB_H 2048
#define GRID_H 1024       // 512 per b, block=512, 4 px/thread
#define PXB_A 2048
#define GRID_A 1024       // 512 per b, block=256, 8 px/thread
#define NPART_A 512

#define STEP_T (0.1f/31.0f)
#define STEP_Y (1.6f/799.0f)
#define STEP_X (4.16f/1999.0f)

// ws float-offset layout
#define OFF_CNT 0        // 16: per-seg pixel count
#define OFF_PRM 32       // 128: seg*8 + {Bt, By, Bx, A, C, var_k, present, pad}
#define OFF_GH2 512      // u64 seg-hist [16][256] -> floats 512..8704
#define OFF_PARTA 9216   // k_acc partials [b*48+f][512] = 49152 floats
#define OFF_SEED2 59392  // k_hist seed partials float2[1024]
#define OFF_HIST_F 65536 // partial hists u32 [1024][KK*NB] = 8 MB

typedef float nvf4 __attribute__((ext_vector_type(4)));
typedef int   nvi4 __attribute__((ext_vector_type(4)));

__device__ __forceinline__ float4 ntload4f(const float* p) {
  nvf4 v = __builtin_nontemporal_load((const nvf4*)p);
  return make_float4(v.x, v.y, v.z, v.w);
}
__device__ __forceinline__ int4 ntload4i(const int* p) {
  nvi4 v = __builtin_nontemporal_load((const nvi4*)p);
  return make_int4(v.x, v.y, v.z, v.w);
}

// ---------------- pass 1: per-(b,k) sums in registers, plain-store partials ----------------
__global__ __launch_bounds__(256) void k_acc(const float* __restrict__ pred,
                                             const int* __restrict__ inst,
                                             float* __restrict__ ws) {
  int tid = threadIdx.x, blk = blockIdx.x;
  int b = blk >> 9;
  int rbase = (blk & 511) * PXB_A;
  const float* sig_p = pred + ((size_t)b * 5 << 20) + (3 << 20);
  const int* ip = inst + ((size_t)b << 20);
  float acc[48];
  #pragma unroll
  for (int f = 0; f < 48; ++f) acc[f] = 0.f;
  #pragma unroll
  for (int it = 0; it < 2; ++it) {
    int r = rbase + it * 1024 + 4 * tid;
    float4 sg4 = ntload4f(sig_p + r);
    int4 id4 = ntload4i(ip + r);
    float tf = (float)(r >> 17), hf = (float)((r >> 9) & 255), wf = (float)(r & 511);
    float sv[4] = {sg4.x, sg4.y, sg4.z, sg4.w};
    int iv[4] = {id4.x, id4.y, id4.z, id4.w};
    #pragma unroll
    for (int j = 0; j < 4; ++j) {
      #pragma unroll
      for (int k = 0; k < KK; ++k) {
        float m = (iv[j] == k + 1) ? 1.f : 0.f;
        acc[k*6+0] += m;
        acc[k*6+1] += m * sv[j];
        acc[k*6+2] += m * sv[j] * sv[j];
        acc[k*6+3] += m * tf;
        acc[k*6+4] += m * hf;
        acc[k*6+5] += m * (wf + (float)j);
      }
    }
  }
  __shared__ float lds[4 * 48];
  int lane = tid & 63, wv = tid >> 6;
  #pragma unroll
  for (int f = 0; f < 48; ++f) {
    float v = acc[f];
    for (int o = 32; o; o >>= 1) v += __shfl_down(v, o);
    if (lane == 0) lds[wv * 48 + f] = v;
  }
  __syncthreads();
  if (tid < 48)
    ws[OFF_PARTA + ((size_t)b * 48 + tid) * NPART_A + (blk & 511)]
      = lds[tid] + lds[48 + tid] + lds[96 + tid] + lds[144 + tid];
}

// ---------------- pass 1b: reduce partials, derive params (1 block) ----------------
__global__ __launch_bounds__(256) void k_params(float* __restrict__ ws) {
  __shared__ float accs[96];
  int tid = threadIdx.x;
  if (tid < 96) {
    const float* p = ws + OFF_PARTA + (size_t)tid * NPART_A;
    float s0 = 0.f, s1 = 0.f, s2 = 0.f, s3 = 0.f;
    for (int j = 0; j < NPART_A; j += 4) {
      s0 += p[j]; s1 += p[j+1]; s2 += p[j+2]; s3 += p[j+3];
    }
    accs[tid] = (s0 + s1) + (s2 + s3);
  }
  __syncthreads();
  if (tid < 16) {
    float* a = &accs[(tid >> 3) * 48 + (tid & 7) * 6];
    float cnt = a[0], s1 = a[1], s2 = a[2], st = a[3], sy = a[4], sx = a[5];
    float safe = fmaxf(cnt, 1.f);
    float smean = s1 / safe;
    float A = __expf(10.f * smean);
    float ct = st * STEP_T / safe;
    float cy = sy * STEP_Y / safe;
    float cx = sx * STEP_X / safe;
    ws[OFF_CNT + tid] = cnt;
    ws[OFF_PRM + tid*8 + 0] = 2.f * A * ct;
    ws[OFF_PRM + tid*8 + 1] = 2.f * A * cy;
    ws[OFF_PRM + tid*8 + 2] = 2.f * A * cx;
    ws[OFF_PRM + tid*8 + 3] = A;
    ws[OFF_PRM + tid*8 + 4] = A * (ct*ct + cy*cy + cx*cx);
    ws[OFF_PRM + tid*8 + 5] = s2 / safe - smean * smean;   // var_k
    ws[OFF_PRM + tid*8 + 6] = (cnt > 0.f) ? 1.f : 0.f;
    ws[OFF_PRM + tid*8 + 7] = 0.f;
  }
}

__device__ __forceinline__ float fast_tanh(float x) {
  x = fminf(fmaxf(x, -15.f), 15.f);
  float ex = __expf(2.f * x);
  return (ex - 1.f) / (ex + 1.f);
}

// ---------------- pass 2: LDS-private histogram, dot-form dist, 1-ballot hot bin ----------------
__global__ __launch_bounds__(512, 8) void k_hist(const float* __restrict__ pred,
                                                 const int* __restrict__ inst,
                                                 float* __restrict__ ws) {
  __shared__ unsigned int hist[KK * NB];  // packed: neg low16, pos high16
  __shared__ float Ps[KK * 8];
  __shared__ float wred[16];
  int tid = threadIdx.x;
  int blk = blockIdx.x;
  int b = blk >> 9;
  for (int i = tid; i < KK * NB; i += 512) hist[i] = 0u;
  if (tid < KK * 8) Ps[tid] = ws[OFF_PRM + b * 64 + tid];
  __syncthreads();
  unsigned pmask = 0;
  #pragma unroll
  for (int k = 0; k < KK; ++k) if (Ps[k*8 + 6] > 0.f) pmask |= 1u << k;
  int r = (blk & 511) * PXB_H + 4 * tid;
  const float* pb = pred + ((size_t)b * 5 << 20);
  float tf = (float)(r >> 17), hf = (float)((r >> 9) & 255);
  int w = r & 511;
  float4 p0 = ntload4f(pb + r);
  float4 p1 = ntload4f(pb + (1 << 20) + r);
  float4 p2 = ntload4f(pb + (2 << 20) + r);
  float4 p4 = ntload4f(pb + (4 << 20) + r);
  int4 id4 = ntload4i(inst + ((size_t)b << 20) + r);
  int iv[4] = {id4.x, id4.y, id4.z, id4.w};
  float e0[4], e1[4], e2[4], ee[4], sd[4];
  {
    float q0[4] = {p0.x,p0.y,p0.z,p0.w}, q1[4] = {p1.x,p1.y,p1.z,p1.w};
    float q2[4] = {p2.x,p2.y,p2.z,p2.w}, q4[4] = {p4.x,p4.y,p4.z,p4.w};
    #pragma unroll
    for (int j = 0; j < 4; ++j) {
      e0[j] = fast_tanh(q0[j]) + tf * STEP_T;
      e1[j] = fast_tanh(q1[j]) + hf * STEP_Y;
      e2[j] = fast_tanh(q2[j]) + (float)(w + j) * STEP_X;
      ee[j] = e0[j]*e0[j] + e1[j]*e1[j] + e2[j]*e2[j];
      sd[j] = 1.f / (1.f + __expf(-q4[j]));
    }
  }
  float sbg = 0.f, sfg = 0.f;
  #pragma unroll
  for (int j = 0; j < 4; ++j) if (iv[j] == 0) sbg += sd[j] * sd[j];
  int lane = tid & 63;
  unsigned hot[KK];
  #pragma unroll
  for (int k = 0; k < KK; ++k) hot[k] = 0u;
  #pragma unroll
  for (int k = 0; k < KK; ++k) {
    if (!((pmask >> k) & 1)) continue;   // block-uniform
    float Bt = Ps[k*8+0], By = Ps[k*8+1], Bx = Ps[k*8+2], A = Ps[k*8+3], C = Ps[k*8+4];
    #pragma unroll
    for (int j = 0; j < 4; ++j) {
      float ssq = fmaf(-Bt, e0[j], fmaf(-By, e1[j], fmaf(-Bx, e2[j], fmaf(A, ee[j], C))));
      bool lab = (iv[j] == k + 1);
      bool skip = (ssq >= FAR_CUT) && !lab;   // !lab far <=> bin 0
      unsigned long long ms = __ballot(skip);
      hot[k] += (unsigned)__popcll(ms);
      if (!skip) {                            // execz-skips when whole wave far
        float d = __expf(-ssq);
        if (lab) { float df = sd[j] - d; sfg += df * df; }
        float e = lab ? (2.f - 2.f * d) : (2.f * d);
        int bin = min((int)(e * HALF_NB_F), NB - 1);
        atomicAdd(&hist[k * NB + bin], lab ? 0x10000u : 1u);
      }
    }
  }
  if (lane == 0) {
    #pragma unroll
    for (int k = 0; k < KK; ++k)
      if (hot[k]) atomicAdd(&hist[k * NB], hot[k]);
  }
  for (int off = 32; off; off >>= 1) {
    sbg += __shfl_down(sbg, off);
    sfg += __shfl_down(sfg, off);
  }
  if (lane == 0) { wred[(tid >> 6) * 2] = sbg; wred[(tid >> 6) * 2 + 1] = sfg; }
  __syncthreads();
  if (tid == 0) {
    float b0 = 0.f, f0 = 0.f;
    #pragma unroll
    for (int v = 0; v < 8; ++v) { b0 += wred[v*2]; f0 += wred[v*2+1]; }
    ((float2*)(ws + OFF_SEED2))[blk] = make_float2(b0, f0);
  }
  // plain coalesced uint4 flush (512 threads x 1 uint4 = 2048 words)
  uint4* gp = (uint4*)((unsigned int*)(ws + OFF_HIST_F) + (size_t)blk * (KK * NB));
  gp[tid] = ((const uint4*)hist)[tid];
}

// ---------------- pass 3a: reduce partial hists -> seg-hist (exclusive, plain stores) ----------------
__global__ __launch_bounds__(256) void k_red(float* __restrict__ ws) {
  int blk = blockIdx.x;               // 256 blocks: seg = blk>>4, bin-range = blk&15
  int tid = threadIdx.x;
  int seg = blk >> 4, range = blk & 15;
  int b = seg >> 3, k = seg & 7;
  __shared__ unsigned long long sred[256];
  int bin_off = tid & 15;
  int pgrp = tid >> 4;                // 16 groups, each sums 32 partials
  const unsigned int* gh = (const unsigned int*)(ws + OFF_HIST_F);
  size_t base = ((size_t)b * 512 + (size_t)pgrp * 32) * (KK * NB)
              + (size_t)k * NB + (size_t)range * 16 + bin_off;
  unsigned int neg = 0, pos = 0;
  #pragma unroll 4
  for (int j = 0; j < 32; ++j) {
    unsigned v = gh[base + (size_t)j * (KK * NB)];
    neg += v & 0xFFFFu; pos += v >> 16;
  }
  sred[tid] = ((unsigned long long)pos << 32) | neg;
  __syncthreads();
  if (tid < 16) {
    unsigned long long a = 0;
    #pragma unroll
    for (int j = 0; j < 16; ++j) a += sred[tid + j * 16];
    ((unsigned long long*)(ws + OFF_GH2))[seg * NB + range * 16 + tid] = a;
  }
}

// ---------------- pass 3b: seed reduce + Lovasz scans + final (1 block) ----------------
__global__ __launch_bounds__(256) void k_fin(float* __restrict__ ws, float* __restrict__ out) {
  int tid = threadIdx.x;
  int lane = tid & 63, wv = tid >> 6;
  __shared__ double segtot[16];
  __shared__ float sdb[4], sdf[4];
  // seed-partial reduction: 1024 float2; waves 0-1 -> b0, waves 2-3 -> b1
  {
    const float2* sp = (const float2*)(ws + OFF_SEED2);
    float sb = 0.f, sf = 0.f;
    #pragma unroll
    for (int j = 0; j < 4; ++j) { float2 v = sp[tid * 4 + j]; sb += v.x; sf += v.y; }
    for (int o = 32; o; o >>= 1) { sb += __shfl_down(sb, o); sf += __shfl_down(sf, o); }
    if (lane == 0) { sdb[wv] = sb; sdf[wv] = sf; }
  }
  // Lovasz scans: 4 waves x 4 segs
  const unsigned long long* gh2 = (const unsigned long long*)(ws + OFF_GH2);
  for (int s = wv; s < 16; s += 4) {
    double total = 0.0;
    if (ws[OFF_PRM + s*8 + 6] != 0.f) {
      double gts = (double)ws[OFF_CNT + s];
      unsigned long long carry = 0;
      double sum = 0.0;
      for (int c = 0; c < NB / 64; ++c) {
        int bin = NB - 1 - (c * 64 + lane);   // descending-error order
        unsigned long long v = gh2[s * NB + bin];
        unsigned long long orig = v;
        #pragma unroll
        for (int o = 1; o < 64; o <<= 1) {
          unsigned long long u = (unsigned long long)__shfl_up((long long)v, o, 64);
          if (lane >= o) v += u;
        }
        v += carry;
        if (orig) {
          unsigned int ip = (unsigned)(v >> 32), in_ = (unsigned)v;
          unsigned int ppx = (unsigned)(orig >> 32), nnx = (unsigned)orig;
          double ep = (double)(ip - ppx), en = (double)(in_ - nnx);
          double js = 1.0 - (gts - ep) / (gts + en);
          double je = 1.0 - (gts - (double)ip) / (gts + (double)in_);
          sum += ((double)bin + 0.5) * (2.0 / NB) * (je - js);
        }
        carry = (unsigned long long)__shfl((long long)v, 63, 64);
      }
      for (int o = 32; o; o >>= 1) sum += __shfl_down(sum, o);
      total = sum;
    }
    if (lane == 0) segtot[s] = total;
  }
  __syncthreads();
  if (tid == 0) {
    double tot = 0.0;
    for (int bb = 0; bb < BB; ++bb) {
      double il = 0.0, vl = 0.0, ob = 0.0;
      for (int k2 = 0; k2 < KK; ++k2) {
        int s2 = bb * 8 + k2;
        double pr = (double)ws[OFF_PRM + s2*8 + 6];
        il += segtot[s2] * pr;
        vl += (double)ws[OFF_PRM + s2*8 + 5] * pr;
        ob += pr;
      }
      double so = (ob > 1.0) ? ob : 1.0;
      double sbg = (double)sdb[bb * 2] + (double)sdb[bb * 2 + 1];
      double sfg = (double)sdf[bb * 2] + (double)sdf[bb * 2 + 1];
      tot += il / so + 10.0 * vl / so + (sbg + sfg) / (256.0 * 512.0);
    }
    out[0] = (float)(tot / BB);
  }
}

extern "C" void kernel_launch(void* const* d_in, const int* in_sizes, int n_in,
                              void* d_out, int out_size, void* d_ws, size_t ws_size,
                              hipStream_t stream) {
  const float* pred = (const float*)d_in[0];
  const int* inst = (const int*)d_in[1];
  float* ws = (float*)d_ws;
  float* out = (float*)d_out;
  k_acc<<<GRID_A, 256, 0, stream>>>(pred, inst, ws);
  k_params<<<1, 256, 0, stream>>>(ws);
  k_hist<<<GRID_H, 512, 0, stream>>>(pred, inst, ws);
  k_red<<<256, 256, 0, stream>>>(ws);
  k_fin<<<1, 256, 0, stream>>>(ws, out);
}

// Round 10
// 136.755 us; speedup vs baseline: 1.0689x; 1.0689x over previous
//
#include <hip/hip_runtime.h>
#include <math.h>

#define BB 2
#define KK 8
#define NB 256            // histogram bins over error in [0,2]
#define HALF_NB_F 128.0f
#define FAR_CUT 5.545177444479562f  // ln(256): d<=1/256 => bin0 (non-lab) / bin255 (lab)

#define PXB_H 2048
#define GRID_H 1024       // 512 per b, block=512, 4 px/thread
#define GRID_A 256        // 128 per b, block=512, 16 px/thread
#define NPART_A 128

#define STEP_T (0.1f/31.0f)
#define STEP_Y (1.6f/799.0f)
#define STEP_X (4.16f/1999.0f)

// ws float-offset layout
#define OFF_CNT 0        // 16: per-seg pixel count (written by k_hist designated blocks)
#define OFF_PRM 32       // 128: seg*8 + {.,.,.,.,., var_k, present, .} for k_fin
#define OFF_GH2 512      // u64 seg-hist [16][256] -> floats 512..8704
#define OFF_PARTA 9216   // k_acc partials [b*48+f][128] = 12288 floats
#define OFF_SEED2 25600  // k_hist seed partials float2[1024]
#define OFF_HIST_F 32768 // partial hists u32 [1024][KK*NB] = 8 MB

typedef float nvf4 __attribute__((ext_vector_type(4)));
typedef int   nvi4 __attribute__((ext_vector_type(4)));

__device__ __forceinline__ float4 ntload4f(const float* p) {
  nvf4 v = __builtin_nontemporal_load((const nvf4*)p);
  return make_float4(v.x, v.y, v.z, v.w);
}
__device__ __forceinline__ int4 ntload4i(const int* p) {
  nvi4 v = __builtin_nontemporal_load((const nvi4*)p);
  return make_int4(v.x, v.y, v.z, v.w);
}

// ---------------- pass 1: per-(b,k) sums in registers, plain-store partials ----------------
__global__ __launch_bounds__(512) void k_acc(const float* __restrict__ pred,
                                             const int* __restrict__ inst,
                                             float* __restrict__ ws) {
  int tid = threadIdx.x, blk = blockIdx.x;
  int b = blk >> 7;
  int rbase = (blk & 127) * 8192;
  const float* sig_p = pred + ((size_t)b * 5 << 20) + (3 << 20);
  const int* ip = inst + ((size_t)b << 20);
  float acc[48];
  #pragma unroll
  for (int f = 0; f < 48; ++f) acc[f] = 0.f;
  #pragma unroll
  for (int it = 0; it < 4; ++it) {
    int r = rbase + it * 2048 + 4 * tid;
    float4 sg4 = ntload4f(sig_p + r);
    int4 id4 = ntload4i(ip + r);
    float tf = (float)(r >> 17), hf = (float)((r >> 9) & 255), wf = (float)(r & 511);
    float sv[4] = {sg4.x, sg4.y, sg4.z, sg4.w};
    int iv[4] = {id4.x, id4.y, id4.z, id4.w};
    #pragma unroll
    for (int j = 0; j < 4; ++j) {
      #pragma unroll
      for (int k = 0; k < KK; ++k) {
        float m = (iv[j] == k + 1) ? 1.f : 0.f;
        acc[k*6+0] += m;
        acc[k*6+1] += m * sv[j];
        acc[k*6+2] += m * sv[j] * sv[j];
        acc[k*6+3] += m * tf;
        acc[k*6+4] += m * hf;
        acc[k*6+5] += m * (wf + (float)j);
      }
    }
  }
  __shared__ float lds[8 * 48];
  int lane = tid & 63, wv = tid >> 6;
  #pragma unroll
  for (int f = 0; f < 48; ++f) {
    float v = acc[f];
    for (int o = 32; o; o >>= 1) v += __shfl_down(v, o);
    if (lane == 0) lds[wv * 48 + f] = v;
  }
  __syncthreads();
  if (tid < 48) {
    float s = 0.f;
    #pragma unroll
    for (int w8 = 0; w8 < 8; ++w8) s += lds[w8 * 48 + tid];
    ws[OFF_PARTA + ((size_t)b * 48 + tid) * NPART_A + (blk & 127)] = s;
  }
}

__device__ __forceinline__ float fast_tanh(float x) {
  x = fminf(fmaxf(x, -15.f), 15.f);
  float ex = __expf(2.f * x);
  return (ex - 1.f) / (ex + 1.f);
}

// ---------------- pass 2: per-block param derive + LDS histogram + plain-store flush ----------------
__global__ __launch_bounds__(512, 8) void k_hist(const float* __restrict__ pred,
                                                 const int* __restrict__ inst,
                                                 float* __restrict__ ws) {
  __shared__ unsigned int hist[KK * NB];  // packed: neg low16, pos high16
  __shared__ float fred[48 * 8];
  __shared__ float accs[48];
  __shared__ float Ps[KK * 8];            // {Bt,By,Bx,A,C,present,cnt,varl}
  __shared__ float wred[16];
  int tid = threadIdx.x;
  int blk = blockIdx.x;
  int b = blk >> 9;
  for (int i = tid; i < KK * NB; i += 512) hist[i] = 0u;
  // --- reduce k_acc partials (L2-hot, redundant per block) ---
  if (tid < 384) {
    int f = tid >> 3, g = tid & 7;
    const float* p = ws + OFF_PARTA + ((size_t)b * 48 + f) * NPART_A + g * 16;
    float s = 0.f;
    #pragma unroll
    for (int j = 0; j < 16; ++j) s += p[j];
    fred[f * 8 + g] = s;
  }
  __syncthreads();
  if (tid < 48) {
    const float* q = &fred[tid * 8];
    accs[tid] = ((q[0]+q[1])+(q[2]+q[3])) + ((q[4]+q[5])+(q[6]+q[7]));
  }
  __syncthreads();
  if (tid < 8) {
    const float* a = &accs[tid * 6];
    float cnt = a[0], s1 = a[1], s2 = a[2], st = a[3], sy = a[4], sx = a[5];
    float safe = fmaxf(cnt, 1.f);
    float smean = s1 / safe;
    float A = __expf(10.f * smean);
    float ct = st * STEP_T / safe;
    float cy = sy * STEP_Y / safe;
    float cx = sx * STEP_X / safe;
    float var = s2 / safe - smean * smean;
    float pres = (cnt > 0.f) ? 1.f : 0.f;
    Ps[tid*8 + 0] = 2.f * A * ct;
    Ps[tid*8 + 1] = 2.f * A * cy;
    Ps[tid*8 + 2] = 2.f * A * cx;
    Ps[tid*8 + 3] = A;
    Ps[tid*8 + 4] = A * (ct*ct + cy*cy + cx*cx);
    Ps[tid*8 + 5] = pres;
    if ((blk & 511) == 0) {          // designated writer for k_fin's inputs
      int seg = b * 8 + tid;
      ws[OFF_CNT + seg] = cnt;
      ws[OFF_PRM + seg*8 + 5] = var;
      ws[OFF_PRM + seg*8 + 6] = pres;
    }
  }
  __syncthreads();
  unsigned pmask = 0;
  #pragma unroll
  for (int k = 0; k < KK; ++k) if (Ps[k*8 + 5] > 0.f) pmask |= 1u << k;
  int r = (blk & 511) * PXB_H + 4 * tid;
  const float* pb = pred + ((size_t)b * 5 << 20);
  float tf = (float)(r >> 17), hf = (float)((r >> 9) & 255);
  int w = r & 511;
  float4 p0 = ntload4f(pb + r);
  float4 p1 = ntload4f(pb + (1 << 20) + r);
  float4 p2 = ntload4f(pb + (2 << 20) + r);
  float4 p4 = ntload4f(pb + (4 << 20) + r);
  int4 id4 = ntload4i(inst + ((size_t)b << 20) + r);
  int iv[4] = {id4.x, id4.y, id4.z, id4.w};
  float e0[4], e1[4], e2[4], ee[4], sd[4];
  {
    float q0[4] = {p0.x,p0.y,p0.z,p0.w}, q1[4] = {p1.x,p1.y,p1.z,p1.w};
    float q2[4] = {p2.x,p2.y,p2.z,p2.w}, q4[4] = {p4.x,p4.y,p4.z,p4.w};
    #pragma unroll
    for (int j = 0; j < 4; ++j) {
      e0[j] = fast_tanh(q0[j]) + tf * STEP_T;
      e1[j] = fast_tanh(q1[j]) + hf * STEP_Y;
      e2[j] = fast_tanh(q2[j]) + (float)(w + j) * STEP_X;
      ee[j] = e0[j]*e0[j] + e1[j]*e1[j] + e2[j]*e2[j];
      sd[j] = 1.f / (1.f + __expf(-q4[j]));
    }
  }
  float sbg = 0.f, sfg = 0.f;
  #pragma unroll
  for (int j = 0; j < 4; ++j) if (iv[j] == 0) sbg += sd[j] * sd[j];
  int lane = tid & 63;
  unsigned hot[KK];                  // per-lane: far counts, neg low16 / pos high16
  #pragma unroll
  for (int k = 0; k < KK; ++k) hot[k] = 0u;
  #pragma unroll
  for (int k = 0; k < KK; ++k) {
    if (!((pmask >> k) & 1)) continue;   // block-uniform
    float Bt = Ps[k*8+0], By = Ps[k*8+1], Bx = Ps[k*8+2], A = Ps[k*8+3], C = Ps[k*8+4];
    #pragma unroll
    for (int j = 0; j < 4; ++j) {
      float ssq = fmaf(-Bt, e0[j], fmaf(-By, e1[j], fmaf(-Bx, e2[j], fmaf(A, ee[j], C))));
      bool lab = (iv[j] == k + 1);
      if (ssq >= FAR_CUT) {              // d<=1/256: lab->bin255(pos), else bin0(neg)
        hot[k] += lab ? 0x10000u : 1u;
        if (lab) sfg += sd[j] * sd[j];   // d~0 approx, error <= 2/256 per px
      } else {
        float d = __expf(-ssq);
        float e;
        if (lab) { float df = sd[j] - d; sfg += df * df; e = 2.f - 2.f * d; }
        else e = 2.f * d;
        int bin = min((int)(e * HALF_NB_F), NB - 1);
        atomicAdd(&hist[k * NB + bin], lab ? 0x10000u : 1u);
      }
    }
  }
  #pragma unroll
  for (int k = 0; k < KK; ++k) {
    unsigned v = hot[k];
    for (int o = 32; o; o >>= 1) v += __shfl_down(v, o);
    if (lane == 0 && v) {
      unsigned neg = v & 0xFFFFu, pos = v & 0xFFFF0000u;
      if (neg) atomicAdd(&hist[k * NB], neg);
      if (pos) atomicAdd(&hist[k * NB + NB - 1], pos);
    }
  }
  for (int off = 32; off; off >>= 1) {
    sbg += __shfl_down(sbg, off);
    sfg += __shfl_down(sfg, off);
  }
  if (lane == 0) { wred[(tid >> 6) * 2] = sbg; wred[(tid >> 6) * 2 + 1] = sfg; }
  __syncthreads();
  if (tid == 0) {
    float b0 = 0.f, f0 = 0.f;
    #pragma unroll
    for (int v = 0; v < 8; ++v) { b0 += wred[v*2]; f0 += wred[v*2+1]; }
    ((float2*)(ws + OFF_SEED2))[blk] = make_float2(b0, f0);
  }
  // plain coalesced uint4 flush (512 threads x 1 uint4 = 2048 words)
  uint4* gp = (uint4*)((unsigned int*)(ws + OFF_HIST_F) + (size_t)blk * (KK * NB));
  gp[tid] = ((const uint4*)hist)[tid];
}

// ---------------- pass 3a: reduce partial hists -> seg-hist (exclusive, plain stores) ----------------
__global__ __launch_bounds__(256) void k_red(float* __restrict__ ws) {
  int blk = blockIdx.x;               // 256 blocks: seg = blk>>4, bin-range = blk&15
  int tid = threadIdx.x;
  int seg = blk >> 4, range = blk & 15;
  int b = seg >> 3, k = seg & 7;
  __shared__ unsigned long long sred[256];
  int bin_off = tid & 15;
  int pgrp = tid >> 4;                // 16 groups, each sums 32 partials
  const unsigned int* gh = (const unsigned int*)(ws + OFF_HIST_F);
  size_t base = ((size_t)b * 512 + (size_t)pgrp * 32) * (KK * NB)
              + (size_t)k * NB + (size_t)range * 16 + bin_off;
  unsigned int neg = 0, pos = 0;
  #pragma unroll 4
  for (int j = 0; j < 32; ++j) {
    unsigned v = gh[base + (size_t)j * (KK * NB)];
    neg += v & 0xFFFFu; pos += v >> 16;
  }
  sred[tid] = ((unsigned long long)pos << 32) | neg;
  __syncthreads();
  if (tid < 16) {
    unsigned long long a = 0;
    #pragma unroll
    for (int j = 0; j < 16; ++j) a += sred[tid + j * 16];
    ((unsigned long long*)(ws + OFF_GH2))[seg * NB + range * 16 + tid] = a;
  }
}

// ---------------- pass 3b: seed reduce + Lovasz scans + final (1 block) ----------------
__global__ __launch_bounds__(256) void k_fin(float* __restrict__ ws, float* __restrict__ out) {
  int tid = threadIdx.x;
  int lane = tid & 63, wv = tid >> 6;
  __shared__ double segtot[16];
  __shared__ float sdb[4], sdf[4];
  // seed-partial reduction: 1024 float2; waves 0-1 -> b0, waves 2-3 -> b1
  {
    const float2* sp = (const float2*)(ws + OFF_SEED2);
    float sb = 0.f, sf = 0.f;
    #pragma unroll
    for (int j = 0; j < 4; ++j) { float2 v = sp[tid * 4 + j]; sb += v.x; sf += v.y; }
    for (int o = 32; o; o >>= 1) { sb += __shfl_down(sb, o); sf += __shfl_down(sf, o); }
    if (lane == 0) { sdb[wv] = sb; sdf[wv] = sf; }
  }
  // Lovasz scans: 4 waves x 4 segs
  const unsigned long long* gh2 = (const unsigned long long*)(ws + OFF_GH2);
  for (int s = wv; s < 16; s += 4) {
    double total = 0.0;
    if (ws[OFF_PRM + s*8 + 6] != 0.f) {
      double gts = (double)ws[OFF_CNT + s];
      unsigned long long carry = 0;
      double sum = 0.0;
      for (int c = 0; c < NB / 64; ++c) {
        int bin = NB - 1 - (c * 64 + lane);   // descending-error order
        unsigned long long v = gh2[s * NB + bin];
        unsigned long long orig = v;
        #pragma unroll
        for (int o = 1; o < 64; o <<= 1) {
          unsigned long long u = (unsigned long long)__shfl_up((long long)v, o, 64);
          if (lane >= o) v += u;
        }
        v += carry;
        if (orig) {
          unsigned int ip = (unsigned)(v >> 32), in_ = (unsigned)v;
          unsigned int ppx = (unsigned)(orig >> 32), nnx = (unsigned)orig;
          double ep = (double)(ip - ppx), en = (double)(in_ - nnx);
          double js = 1.0 - (gts - ep) / (gts + en);
          double je = 1.0 - (gts - (double)ip) / (gts + (double)in_);
          sum += ((double)bin + 0.5) * (2.0 / NB) * (je - js);
        }
        carry = (unsigned long long)__shfl((long long)v, 63, 64);
      }
      for (int o = 32; o; o >>= 1) sum += __shfl_down(sum, o);
      total = sum;
    }
    if (lane == 0) segtot[s] = total;
  }
  __syncthreads();
  if (tid == 0) {
    double tot = 0.0;
    for (int bb = 0; bb < BB; ++bb) {
      double il = 0.0, vl = 0.0, ob = 0.0;
      for (int k2 = 0; k2 < KK; ++k2) {
        int s2 = bb * 8 + k2;
        double pr = (double)ws[OFF_PRM + s2*8 + 6];
        il += segtot[s2] * pr;
        vl += (double)ws[OFF_PRM + s2*8 + 5] * pr;
        ob += pr;
      }
      double so = (ob > 1.0) ? ob : 1.0;
      double sbg = (double)sdb[bb * 2] + (double)sdb[bb * 2 + 1];
      double sfg = (double)sdf[bb * 2] + (double)sdf[bb * 2 + 1];
      tot += il / so + 10.0 * vl / so + (sbg + sfg) / (256.0 * 512.0);
    }
    out[0] = (float)(tot / BB);
  }
}

extern "C" void kernel_launch(void* const* d_in, const int* in_sizes, int n_in,
                              void* d_out, int out_size, void* d_ws, size_t ws_size,
                              hipStream_t stream) {
  const float* pred = (const float*)d_in[0];
  const int* inst = (const int*)d_in[1];
  float* ws = (float*)d_ws;
  float* out = (float*)d_out;
  k_acc<<<GRID_A, 512, 0, stream>>>(pred, inst, ws);
  k_hist<<<GRID_H, 512, 0, stream>>>(pred, inst, ws);
  k_red<<<256, 256, 0, stream>>>(ws);
  k_fin<<<1, 256, 0, stream>>>(ws, out);
}